// Round 1
// baseline (620.208 us; speedup 1.0000x reference)
//
#include <hip/hip_runtime.h>

typedef unsigned short u16;
typedef unsigned int u32;
typedef __attribute__((ext_vector_type(8))) short short8;
typedef __attribute__((ext_vector_type(4))) float f32x4;

#define NN 50000
#define EE 800000

__device__ __forceinline__ float b2f(u16 u){ union{float f;u32 i;}x; x.i=((u32)u)<<16; return x.f; }
__device__ __forceinline__ u16 f2b(float f){ union{float f;u32 i;}x; x.f=f; u32 i=x.i; return (u16)((i + 0x7fffu + ((i>>16)&1u))>>16); }

// ---------- converts ----------
__global__ void k_f2b4(const float* __restrict__ x, u16* __restrict__ y, int n4){
  int i = blockIdx.x*256 + threadIdx.x;
  if (i >= n4) return;
  float4 v = ((const float4*)x)[i];
  ushort4 o; o.x=f2b(v.x); o.y=f2b(v.y); o.z=f2b(v.z); o.w=f2b(v.w);
  ((ushort4*)y)[i]=o;
}

// ---------- CSR build ----------
__global__ void k_count(const int* __restrict__ dst, int* __restrict__ cnt){
  int i = blockIdx.x*256+threadIdx.x; if (i<EE) atomicAdd(&cnt[dst[i]],1);
}

__global__ void k_scan_blocks(const int* __restrict__ cnt, int* __restrict__ off, int* __restrict__ part, int n){
  __shared__ int ts[256];
  int t = threadIdx.x; int base = blockIdx.x*1024 + t*4;
  int c0 = (base+0<n)?cnt[base+0]:0;
  int c1 = (base+1<n)?cnt[base+1]:0;
  int c2 = (base+2<n)?cnt[base+2]:0;
  int c3 = (base+3<n)?cnt[base+3]:0;
  int s = c0+c1+c2+c3;
  ts[t]=s; __syncthreads();
  for (int d=1; d<256; d<<=1){ int v=(t>=d)?ts[t-d]:0; __syncthreads(); ts[t]+=v; __syncthreads(); }
  int ex = ts[t]-s;
  if (t==255) part[blockIdx.x]=ts[255];
  if (base+0<n) off[base+0]=ex; ex+=c0;
  if (base+1<n) off[base+1]=ex; ex+=c1;
  if (base+2<n) off[base+2]=ex; ex+=c2;
  if (base+3<n) off[base+3]=ex;
}

__global__ void k_scan_part(int* part, int nb){
  if (threadIdx.x==0 && blockIdx.x==0){ int run=0; for(int i=0;i<nb;++i){ int v=part[i]; part[i]=run; run+=v; } }
}

__global__ void k_addback(int* off, const int* __restrict__ part, int n){
  int base = blockIdx.x*1024 + threadIdx.x*4; int p = part[blockIdx.x];
  #pragma unroll
  for (int j=0;j<4;++j) if (base+j<n) off[base+j]+=p;
}

__global__ void k_copy(const int* __restrict__ a, int* __restrict__ b, int n){
  int i=blockIdx.x*256+threadIdx.x; if(i<n) b[i]=a[i];
}

__global__ void k_scatter(const int* __restrict__ src, const int* __restrict__ dst, int* __restrict__ cur,
                          int* __restrict__ srcs, int* __restrict__ ddst){
  int i = blockIdx.x*256+threadIdx.x; if (i>=EE) return;
  int d = dst[i]; int p = atomicAdd(&cur[d],1);
  srcs[p]=src[i]; ddst[p]=d;
}

// ---------- GEMM: C[M,N] = A[M,256](bf16) @ B[256,N](bf16), f32 acc ----------
template<int OUT_BF16>
__global__ __launch_bounds__(256) void k_gemm(const u16* __restrict__ A, const u16* __restrict__ B,
                                              void* __restrict__ Cv, int M, int N){
  __shared__ u16 Bt[32][264];   // Bt[c][k], padded
  const int tid = threadIdx.x;
  const int n0 = blockIdx.y * 32;
  const int row0 = blockIdx.x * 256;
  for (int idx = tid; idx < 32*256; idx += 256){
    int c = idx & 31, k = idx >> 5;
    Bt[c][k] = B[(size_t)k*N + n0 + c];
  }
  __syncthreads();
  const int w = tid >> 6, l = tid & 63;
  const int lr = l & 15, lq = l >> 4;
  const int wrow = row0 + w*64;
  f32x4 acc[4][2];
  #pragma unroll
  for (int fr=0; fr<4; ++fr)
    #pragma unroll
    for (int j=0; j<2; ++j) acc[fr][j] = (f32x4)0.0f;
  #pragma unroll
  for (int k0 = 0; k0 < 256; k0 += 32){
    short8 a[4], b[2];
    #pragma unroll
    for (int fr=0; fr<4; ++fr){
      int r = wrow + fr*16 + lr; r = r < M ? r : M-1;
      a[fr] = *(const short8*)(A + (size_t)r*256 + k0 + lq*8);
    }
    #pragma unroll
    for (int j=0; j<2; ++j)
      b[j] = *(const short8*)(&Bt[j*16 + lr][k0 + lq*8]);
    #pragma unroll
    for (int fr=0; fr<4; ++fr)
      #pragma unroll
      for (int j=0; j<2; ++j)
        acc[fr][j] = __builtin_amdgcn_mfma_f32_16x16x32_bf16(a[fr], b[j], acc[fr][j], 0, 0, 0);
  }
  #pragma unroll
  for (int fr=0; fr<4; ++fr)
    #pragma unroll
    for (int j=0; j<2; ++j)
      #pragma unroll
      for (int q=0; q<4; ++q){
        int r = wrow + fr*16 + lq*4 + q;
        if (r < M){
          int c = n0 + j*16 + lr;
          if constexpr (OUT_BF16) ((u16*)Cv)[(size_t)r*N + c] = f2b(acc[fr][j][q]);
          else                    ((float*)Cv)[(size_t)r*N + c] = acc[fr][j][q];
        }
      }
}

// ---------- el/er: per (node, head) dot(feat, al/ar) ----------
__global__ void k_eler(const u16* __restrict__ feat, const float* __restrict__ al, const float* __restrict__ ar,
                       float* __restrict__ el, float* __restrict__ er, int Dh, int HD){
  int t = blockIdx.x*256 + threadIdx.x;
  int n = t >> 6; int l = t & 63;
  if (n >= NN) return;
  int h = l >> 4, s = l & 15;
  const u16* fr = feat + (size_t)n*HD + h*Dh;
  const float* alh = al + h*Dh; const float* arh = ar + h*Dh;
  float accl = 0.f, accr = 0.f;
  for (int d = s; d < Dh; d += 16){ float f = b2f(fr[d]); accl += f*alh[d]; accr += f*arh[d]; }
  #pragma unroll
  for (int m = 8; m >= 1; m >>= 1){ accl += __shfl_xor(accl, m, 64); accr += __shfl_xor(accr, m, 64); }
  if (s == 0){ el[n*4+h] = accl; er[n*4+h] = accr; }
}

// ---------- edge scores (leaky relu) ----------
__global__ void k_escore(const float* __restrict__ el, const float* __restrict__ er,
                         const int* __restrict__ srcs, const int* __restrict__ ddst,
                         float* __restrict__ es){
  int i = blockIdx.x*256 + threadIdx.x; if (i >= EE) return;
  float4 a = ((const float4*)el)[srcs[i]];
  float4 b = ((const float4*)er)[ddst[i]];
  float4 v;
  v.x = a.x+b.x; v.x = v.x >= 0.f ? v.x : 0.2f*v.x;
  v.y = a.y+b.y; v.y = v.y >= 0.f ? v.y : 0.2f*v.y;
  v.z = a.z+b.z; v.z = v.z >= 0.f ? v.z : 0.2f*v.z;
  v.w = a.w+b.w; v.w = v.w >= 0.f ? v.w : 0.2f*v.w;
  ((float4*)es)[i] = v;
}

// ---------- per-node softmax: es -> exp(e-m) in place; recs = 1/sum ----------
__global__ void k_softmax(float* __restrict__ es, const int* __restrict__ off, float* __restrict__ recs){
  int n = blockIdx.x*256 + threadIdx.x; if (n >= NN) return;
  int o0 = off[n], o1 = off[n+1];
  float4 m; m.x=m.y=m.z=m.w=-1e30f;
  for (int i=o0;i<o1;++i){ float4 v = ((const float4*)es)[i];
    m.x=fmaxf(m.x,v.x); m.y=fmaxf(m.y,v.y); m.z=fmaxf(m.z,v.z); m.w=fmaxf(m.w,v.w); }
  float4 s; s.x=s.y=s.z=s.w=0.f;
  for (int i=o0;i<o1;++i){ float4 v = ((const float4*)es)[i];
    v.x=__expf(v.x-m.x); v.y=__expf(v.y-m.y); v.z=__expf(v.z-m.z); v.w=__expf(v.w-m.w);
    ((float4*)es)[i]=v; s.x+=v.x; s.y+=v.y; s.z+=v.z; s.w+=v.w; }
  float4 r;
  r.x = s.x>0.f ? 1.f/s.x : 0.f;
  r.y = s.y>0.f ? 1.f/s.y : 0.f;
  r.z = s.z>0.f ? 1.f/s.z : 0.f;
  r.w = s.w>0.f ? 1.f/s.w : 0.f;
  ((float4*)recs)[n] = r;
}

// ---------- aggregation for D=64 layers: wave per node, ELU, optional residual ----------
template<bool RES>
__global__ __launch_bounds__(256) void k_agg64(const u16* __restrict__ feat, const float* __restrict__ es,
    const float* __restrict__ recs, const int* __restrict__ off, const int* __restrict__ srcs,
    const u16* __restrict__ resid, float* __restrict__ outf, u16* __restrict__ outb){
  int l = threadIdx.x & 63, w = threadIdx.x >> 6;
  int n = blockIdx.x*4 + w;
  int o0 = off[n], o1 = off[n+1];
  int h = l >> 4;
  float ax=0.f, ay=0.f, az=0.f, aw=0.f;
  int i = o0;
  for (; i + 2 <= o1; i += 2){
    int s0 = srcs[i], s1 = srcs[i+1];
    float e0 = es[(size_t)i*4 + h], e1 = es[(size_t)(i+1)*4 + h];
    ushort4 f0 = *(const ushort4*)(feat + (size_t)s0*256 + l*4);
    ushort4 f1 = *(const ushort4*)(feat + (size_t)s1*256 + l*4);
    ax += e0*b2f(f0.x) + e1*b2f(f1.x);
    ay += e0*b2f(f0.y) + e1*b2f(f1.y);
    az += e0*b2f(f0.z) + e1*b2f(f1.z);
    aw += e0*b2f(f0.w) + e1*b2f(f1.w);
  }
  if (i < o1){
    int s0 = srcs[i];
    float e0 = es[(size_t)i*4 + h];
    ushort4 f0 = *(const ushort4*)(feat + (size_t)s0*256 + l*4);
    ax += e0*b2f(f0.x); ay += e0*b2f(f0.y); az += e0*b2f(f0.z); aw += e0*b2f(f0.w);
  }
  float rc = recs[n*4+h];
  float vx = ax*rc, vy = ay*rc, vz = az*rc, vw = aw*rc;
  if (RES){
    ushort4 r4 = *(const ushort4*)(resid + (size_t)n*256 + l*4);
    vx += b2f(r4.x); vy += b2f(r4.y); vz += b2f(r4.z); vw += b2f(r4.w);
  }
  vx = vx > 0.f ? vx : expm1f(vx);
  vy = vy > 0.f ? vy : expm1f(vy);
  vz = vz > 0.f ? vz : expm1f(vz);
  vw = vw > 0.f ? vw : expm1f(vw);
  if (outf){ float4 v; v.x=vx; v.y=vy; v.z=vz; v.w=vw; *(float4*)(outf + (size_t)n*256 + l*4) = v; }
  ushort4 ob; ob.x=f2b(vx); ob.y=f2b(vy); ob.z=f2b(vz); ob.w=f2b(vw);
  *(ushort4*)(outb + (size_t)n*256 + l*4) = ob;
}

// ---------- output-layer aggregation: OUT=40, +res_o, mean over heads ----------
__global__ __launch_bounds__(256) void k_agg_out(const u16* __restrict__ feat, const float* __restrict__ es,
    const float* __restrict__ recs, const int* __restrict__ off, const int* __restrict__ srcs,
    const u16* __restrict__ reso, float* __restrict__ logits){
  __shared__ float buf[4][160];
  int l = threadIdx.x & 63, w = threadIdx.x >> 6;
  int n = blockIdx.x*4 + w;
  int o0 = off[n], o1 = off[n+1];
  int d0 = l, d1 = l+64, d2 = l+128;     // d2 valid when l<32
  int h0 = d0/40, h1 = d1/40;            // h2 == 3 always
  float a0=0.f, a1=0.f, a2=0.f;
  for (int i=o0;i<o1;++i){
    const u16* f = feat + (size_t)srcs[i]*160;
    float e0 = es[(size_t)i*4+h0], e1 = es[(size_t)i*4+h1], e2 = es[(size_t)i*4+3];
    a0 += e0*b2f(f[d0]); a1 += e1*b2f(f[d1]);
    if (l < 32) a2 += e2*b2f(f[d2]);
  }
  float4 rc = ((const float4*)recs)[n];
  const float* rcp = (const float*)&rc;
  float v0 = a0*rcp[h0] + b2f(reso[(size_t)n*160 + d0]);
  float v1 = a1*rcp[h1] + b2f(reso[(size_t)n*160 + d1]);
  buf[w][d0]=v0; buf[w][d1]=v1;
  if (l < 32){ float v2 = a2*rcp[3] + b2f(reso[(size_t)n*160 + d2]); buf[w][d2]=v2; }
  __syncthreads();
  if (l < 40) logits[(size_t)n*40 + l] = 0.25f*(buf[w][l]+buf[w][l+40]+buf[w][l+80]+buf[w][l+120]);
}

extern "C" void kernel_launch(void* const* d_in, const int* in_sizes, int n_in,
                              void* d_out, int out_size, void* d_ws, size_t ws_size,
                              hipStream_t stream){
  const float* inputs = (const float*)d_in[0];
  const int*   src    = (const int*)d_in[1];
  const int*   dst    = (const int*)d_in[2];
  const float* W0  = (const float*)d_in[3];
  const float* al0 = (const float*)d_in[4];
  const float* ar0 = (const float*)d_in[5];
  const float* W1  = (const float*)d_in[6];
  const float* al1 = (const float*)d_in[7];
  const float* ar1 = (const float*)d_in[8];
  const float* Wo  = (const float*)d_in[9];
  const float* alo = (const float*)d_in[10];
  const float* aro = (const float*)d_in[11];
  const float* rWo = (const float*)d_in[12];
  const float* fcW = (const float*)d_in[13];

  float* out = (float*)d_out;
  float* out_logits = out;                 // [50000,40]
  float* out_h      = out + 2000000;       // [50000,256]
  float* out_seq    = out + 14800000;      // [50000,64]

  char* ws = (char*)d_ws;
  size_t o = 0;
  auto alc = [&](size_t bytes){ size_t r = o; o += (bytes + 255) & ~(size_t)255; return r; };
  size_t oXb   = alc((size_t)NN*256*2);
  size_t oFA   = alc((size_t)NN*256*2);
  size_t oFB   = alc((size_t)NN*256*2);
  size_t oEs   = alc((size_t)EE*4*4);
  size_t oSrcs = alc((size_t)EE*4);
  size_t oDdst = alc((size_t)EE*4);
  size_t oOff  = alc((size_t)(NN+1)*4);
  size_t oCnt  = alc((size_t)(NN+1)*4);
  size_t oCur  = alc((size_t)NN*4);
  size_t oPart = alc(64*4);
  size_t oEl   = alc((size_t)NN*4*4);
  size_t oEr   = alc((size_t)NN*4*4);
  size_t oRecs = alc((size_t)NN*4*4);
  size_t oReso = alc((size_t)NN*160*2);
  size_t oW0b  = alc(256*256*2);
  size_t oW1b  = alc(256*256*2);
  size_t oWob  = alc(256*160*2);
  size_t oRWob = alc(256*160*2);
  size_t oFcb  = alc(256*64*2);
  if (ws_size < o) return;

  u16* Xb   = (u16*)(ws + oXb);
  u16* fA   = (u16*)(ws + oFA);
  u16* fB   = (u16*)(ws + oFB);
  float* es = (float*)(ws + oEs);
  int* srcs = (int*)(ws + oSrcs);
  int* ddst = (int*)(ws + oDdst);
  int* off  = (int*)(ws + oOff);
  int* cnt  = (int*)(ws + oCnt);
  int* cur  = (int*)(ws + oCur);
  int* part = (int*)(ws + oPart);
  float* el = (float*)(ws + oEl);
  float* er = (float*)(ws + oEr);
  float* recs = (float*)(ws + oRecs);
  u16* reso = (u16*)(ws + oReso);
  u16* W0b  = (u16*)(ws + oW0b);
  u16* W1b  = (u16*)(ws + oW1b);
  u16* Wob  = (u16*)(ws + oWob);
  u16* rWob = (u16*)(ws + oRWob);
  u16* fcb  = (u16*)(ws + oFcb);

  // ---- converts ----
  k_f2b4<<<(NN*256/4 + 255)/256, 256, 0, stream>>>(inputs, Xb, NN*256/4);
  k_f2b4<<<(65536/4 + 255)/256, 256, 0, stream>>>(W0, W0b, 65536/4);
  k_f2b4<<<(65536/4 + 255)/256, 256, 0, stream>>>(W1, W1b, 65536/4);
  k_f2b4<<<(40960/4 + 255)/256, 256, 0, stream>>>(Wo, Wob, 40960/4);
  k_f2b4<<<(40960/4 + 255)/256, 256, 0, stream>>>(rWo, rWob, 40960/4);
  k_f2b4<<<(16384/4 + 255)/256, 256, 0, stream>>>(fcW, fcb, 16384/4);

  // ---- CSR ----
  hipMemsetAsync(cnt, 0, (size_t)(NN+1)*4, stream);
  k_count<<<(EE+255)/256, 256, 0, stream>>>(dst, cnt);
  const int NP1 = NN+1, NB = (NP1 + 1023)/1024;
  k_scan_blocks<<<NB, 256, 0, stream>>>(cnt, off, part, NP1);
  k_scan_part<<<1, 64, 0, stream>>>(part, NB);
  k_addback<<<NB, 256, 0, stream>>>(off, part, NP1);
  k_copy<<<(NN+255)/256, 256, 0, stream>>>(off, cur, NN);
  k_scatter<<<(EE+255)/256, 256, 0, stream>>>(src, dst, cur, srcs, ddst);

  dim3 gN256((NN+255)/256, 8), gN160((NN+255)/256, 5), gN64((NN+255)/256, 2);

  // ---- seq_fts = X @ fc_W (f32 out) ----
  k_gemm<0><<<gN64, 256, 0, stream>>>(Xb, fcb, out_seq, NN, 64);

  // ---- layer 0 ----
  k_gemm<1><<<gN256, 256, 0, stream>>>(Xb, W0b, fA, NN, 256);
  k_eler<<<(NN*64 + 255)/256, 256, 0, stream>>>(fA, al0, ar0, el, er, 64, 256);
  k_escore<<<(EE+255)/256, 256, 0, stream>>>(el, er, srcs, ddst, es);
  k_softmax<<<(NN+255)/256, 256, 0, stream>>>(es, off, recs);
  k_agg64<false><<<NN/4, 256, 0, stream>>>(fA, es, recs, off, srcs, nullptr, nullptr, fB);

  // ---- layer 1 ----
  k_gemm<1><<<gN256, 256, 0, stream>>>(fB, W1b, fA, NN, 256);
  k_eler<<<(NN*64 + 255)/256, 256, 0, stream>>>(fA, al1, ar1, el, er, 64, 256);
  k_escore<<<(EE+255)/256, 256, 0, stream>>>(el, er, srcs, ddst, es);
  k_softmax<<<(NN+255)/256, 256, 0, stream>>>(es, off, recs);
  k_agg64<true><<<NN/4, 256, 0, stream>>>(fA, es, recs, off, srcs, fB, out_h, fB);

  // ---- output layer ----
  k_gemm<1><<<gN160, 256, 0, stream>>>(fB, rWob, reso, NN, 160);
  k_gemm<1><<<gN160, 256, 0, stream>>>(fB, Wob, fA, NN, 160);
  k_eler<<<(NN*64 + 255)/256, 256, 0, stream>>>(fA, alo, aro, el, er, 40, 160);
  k_escore<<<(EE+255)/256, 256, 0, stream>>>(el, er, srcs, ddst, es);
  k_softmax<<<(NN+255)/256, 256, 0, stream>>>(es, off, recs);
  k_agg_out<<<NN/4, 256, 0, stream>>>(fA, es, recs, off, srcs, reso, out_logits);
}

// Round 2
// 566.465 us; speedup vs baseline: 1.0949x; 1.0949x over previous
//
#include <hip/hip_runtime.h>

typedef unsigned short u16;
typedef unsigned int u32;
typedef __attribute__((ext_vector_type(8))) short short8;
typedef __attribute__((ext_vector_type(4))) float f32x4;

#define NN 50000
#define EE 800000

__device__ __forceinline__ float b2f(u16 u){ union{float f;u32 i;}x; x.i=((u32)u)<<16; return x.f; }
__device__ __forceinline__ u16 f2b(float f){ union{float f;u32 i;}x; x.f=f; u32 i=x.i; return (u16)((i + 0x7fffu + ((i>>16)&1u))>>16); }

// ---------- converts ----------
__global__ void k_f2b4(const float* __restrict__ x, u16* __restrict__ y, int n4){
  int i = blockIdx.x*256 + threadIdx.x;
  if (i >= n4) return;
  float4 v = ((const float4*)x)[i];
  ushort4 o; o.x=f2b(v.x); o.y=f2b(v.y); o.z=f2b(v.z); o.w=f2b(v.w);
  ((ushort4*)y)[i]=o;
}

// concat [rWo | Wo] -> Bcat[256][320] bf16
__global__ void k_catWo(const float* __restrict__ rWo, const float* __restrict__ Wo, u16* __restrict__ Bcat){
  int i = blockIdx.x*256 + threadIdx.x;
  if (i >= 256*320) return;
  int k = i/320, c = i%320;
  float v = (c < 160) ? rWo[k*160 + c] : Wo[k*160 + (c-160)];
  Bcat[i] = f2b(v);
}

// ---------- CSR build ----------
__global__ void k_count(const int* __restrict__ dst, int* __restrict__ cnt){
  int i = blockIdx.x*256+threadIdx.x; if (i<EE) atomicAdd(&cnt[dst[i]],1);
}

__global__ void k_scan_blocks(const int* __restrict__ cnt, int* __restrict__ off, int* __restrict__ part, int n){
  __shared__ int ts[256];
  int t = threadIdx.x; int base = blockIdx.x*1024 + t*4;
  int c0 = (base+0<n)?cnt[base+0]:0;
  int c1 = (base+1<n)?cnt[base+1]:0;
  int c2 = (base+2<n)?cnt[base+2]:0;
  int c3 = (base+3<n)?cnt[base+3]:0;
  int s = c0+c1+c2+c3;
  ts[t]=s; __syncthreads();
  for (int d=1; d<256; d<<=1){ int v=(t>=d)?ts[t-d]:0; __syncthreads(); ts[t]+=v; __syncthreads(); }
  int ex = ts[t]-s;
  if (t==255) part[blockIdx.x]=ts[255];
  if (base+0<n) off[base+0]=ex; ex+=c0;
  if (base+1<n) off[base+1]=ex; ex+=c1;
  if (base+2<n) off[base+2]=ex; ex+=c2;
  if (base+3<n) off[base+3]=ex;
}

__global__ void k_scan_part(int* part, int nb){
  if (threadIdx.x==0 && blockIdx.x==0){ int run=0; for(int i=0;i<nb;++i){ int v=part[i]; part[i]=run; run+=v; } }
}

__global__ void k_addback(int* off, const int* __restrict__ part, int n){
  int base = blockIdx.x*1024 + threadIdx.x*4; int p = part[blockIdx.x];
  #pragma unroll
  for (int j=0;j<4;++j) if (base+j<n) off[base+j]+=p;
}

__global__ void k_copy(const int* __restrict__ a, int* __restrict__ b, int n){
  int i=blockIdx.x*256+threadIdx.x; if(i<n) b[i]=a[i];
}

__global__ void k_scatter(const int* __restrict__ src, const int* __restrict__ dst, int* __restrict__ cur,
                          int* __restrict__ srcs){
  int i = blockIdx.x*256+threadIdx.x; if (i>=EE) return;
  int d = dst[i]; int p = atomicAdd(&cur[d],1);
  srcs[p]=src[i];
}

// ---------- GEMM: C[M,N] = A[M,256](bf16) @ B[256,N](bf16), f32 acc, BN=64 ----------
// MODE 0: f32 out (C0). MODE 1: bf16 out (C0). MODE 2: split at col 160 -> C0(reso bf16), C1(fA bf16)
template<int MODE>
__global__ __launch_bounds__(256) void k_gemm(const u16* __restrict__ A, const u16* __restrict__ B,
                                              void* __restrict__ C0, void* __restrict__ C1,
                                              int M, int N){
  __shared__ u16 Bt[64][266];   // Bt[c][k]
  const int tid = threadIdx.x;
  const int n0 = blockIdx.y * 64;
  const int row0 = blockIdx.x * 256;
  #pragma unroll
  for (int r=0; r<32; ++r){
    int lin = r*256 + tid;          // 0..8191
    int kk = lin >> 5;              // 0..255
    int cp = (lin & 31) << 1;       // 0,2,..,62
    ushort2 v = *(const ushort2*)(B + (size_t)kk*N + n0 + cp);
    Bt[cp][kk] = v.x; Bt[cp+1][kk] = v.y;
  }
  __syncthreads();
  const int w = tid >> 6, l = tid & 63;
  const int lr = l & 15, lq = l >> 4;
  const int wrow = row0 + w*64;
  f32x4 acc[4][4];
  #pragma unroll
  for (int fr=0; fr<4; ++fr)
    #pragma unroll
    for (int j=0; j<4; ++j) acc[fr][j] = (f32x4)0.0f;
  #pragma unroll
  for (int k0 = 0; k0 < 256; k0 += 32){
    short8 a[4], b[4];
    #pragma unroll
    for (int fr=0; fr<4; ++fr){
      int r = wrow + fr*16 + lr; r = r < M ? r : M-1;
      a[fr] = *(const short8*)(A + (size_t)r*256 + k0 + lq*8);
    }
    #pragma unroll
    for (int j=0; j<4; ++j)
      b[j] = *(const short8*)(&Bt[j*16 + lr][k0 + lq*8]);
    #pragma unroll
    for (int fr=0; fr<4; ++fr)
      #pragma unroll
      for (int j=0; j<4; ++j)
        acc[fr][j] = __builtin_amdgcn_mfma_f32_16x16x32_bf16(a[fr], b[j], acc[fr][j], 0, 0, 0);
  }
  #pragma unroll
  for (int fr=0; fr<4; ++fr)
    #pragma unroll
    for (int j=0; j<4; ++j)
      #pragma unroll
      for (int q=0; q<4; ++q){
        int r = wrow + fr*16 + lq*4 + q;
        if (r < M){
          int c = n0 + j*16 + lr;
          float v = acc[fr][j][q];
          if constexpr (MODE == 0)      ((float*)C0)[(size_t)r*N + c] = v;
          else if constexpr (MODE == 1) ((u16*)C0)[(size_t)r*N + c] = f2b(v);
          else {
            if (c < 160) ((u16*)C0)[(size_t)r*160 + c]       = f2b(v);
            else         ((u16*)C1)[(size_t)r*160 + (c-160)] = f2b(v);
          }
        }
      }
}

// ---------- el/er: per (node, head) dot(feat, al/ar) ----------
__global__ void k_eler(const u16* __restrict__ feat, const float* __restrict__ al, const float* __restrict__ ar,
                       float* __restrict__ el, float* __restrict__ er, int Dh, int HD){
  int t = blockIdx.x*256 + threadIdx.x;
  int n = t >> 6; int l = t & 63;
  if (n >= NN) return;
  int h = l >> 4, s = l & 15;
  const u16* fr = feat + (size_t)n*HD + h*Dh;
  const float* alh = al + h*Dh; const float* arh = ar + h*Dh;
  float accl = 0.f, accr = 0.f;
  for (int d = s; d < Dh; d += 16){ float f = b2f(fr[d]); accl += f*alh[d]; accr += f*arh[d]; }
  #pragma unroll
  for (int m = 8; m >= 1; m >>= 1){ accl += __shfl_xor(accl, m, 64); accr += __shfl_xor(accr, m, 64); }
  if (s == 0){ el[n*4+h] = accl; er[n*4+h] = accr; }
}

// ---------- fused edge-score + per-node softmax ----------
__global__ void k_soft(const float* __restrict__ el, const float* __restrict__ er,
                       const int* __restrict__ srcs, const int* __restrict__ off,
                       float* __restrict__ es, float* __restrict__ recs){
  int n = blockIdx.x*256 + threadIdx.x; if (n >= NN) return;
  int o0 = off[n], o1 = off[n+1];
  float4 e4 = ((const float4*)er)[n];
  float4 m; m.x=m.y=m.z=m.w=-1e30f;
  for (int i=o0;i<o1;++i){
    float4 a = ((const float4*)el)[srcs[i]];
    float vx=a.x+e4.x; vx = vx>=0.f?vx:0.2f*vx;
    float vy=a.y+e4.y; vy = vy>=0.f?vy:0.2f*vy;
    float vz=a.z+e4.z; vz = vz>=0.f?vz:0.2f*vz;
    float vw=a.w+e4.w; vw = vw>=0.f?vw:0.2f*vw;
    m.x=fmaxf(m.x,vx); m.y=fmaxf(m.y,vy); m.z=fmaxf(m.z,vz); m.w=fmaxf(m.w,vw);
  }
  float4 s; s.x=s.y=s.z=s.w=0.f;
  for (int i=o0;i<o1;++i){
    float4 a = ((const float4*)el)[srcs[i]];
    float vx=a.x+e4.x; vx = vx>=0.f?vx:0.2f*vx;
    float vy=a.y+e4.y; vy = vy>=0.f?vy:0.2f*vy;
    float vz=a.z+e4.z; vz = vz>=0.f?vz:0.2f*vz;
    float vw=a.w+e4.w; vw = vw>=0.f?vw:0.2f*vw;
    float4 v;
    v.x=__expf(vx-m.x); v.y=__expf(vy-m.y); v.z=__expf(vz-m.z); v.w=__expf(vw-m.w);
    ((float4*)es)[i]=v; s.x+=v.x; s.y+=v.y; s.z+=v.z; s.w+=v.w;
  }
  float4 r;
  r.x = s.x>0.f ? 1.f/s.x : 0.f;
  r.y = s.y>0.f ? 1.f/s.y : 0.f;
  r.z = s.z>0.f ? 1.f/s.z : 0.f;
  r.w = s.w>0.f ? 1.f/s.w : 0.f;
  ((float4*)recs)[n] = r;
}

// ---------- aggregation for D=64 layers: wave per node, 4-edge unroll ----------
template<bool RES>
__global__ __launch_bounds__(256) void k_agg64(const u16* __restrict__ feat, const float* __restrict__ es,
    const float* __restrict__ recs, const int* __restrict__ off, const int* __restrict__ srcs,
    const u16* __restrict__ resid, float* __restrict__ outf, u16* __restrict__ outb){
  int l = threadIdx.x & 63, w = threadIdx.x >> 6;
  int n = blockIdx.x*4 + w;
  int o0 = off[n], o1 = off[n+1];
  int h = l >> 4;
  float ax=0.f, ay=0.f, az=0.f, aw=0.f;
  int i = o0;
  for (; i + 4 <= o1; i += 4){
    int s0 = srcs[i], s1 = srcs[i+1], s2 = srcs[i+2], s3 = srcs[i+3];
    float e0 = es[(size_t)i*4 + h],     e1 = es[(size_t)(i+1)*4 + h];
    float e2 = es[(size_t)(i+2)*4 + h], e3 = es[(size_t)(i+3)*4 + h];
    ushort4 f0 = *(const ushort4*)(feat + (size_t)s0*256 + l*4);
    ushort4 f1 = *(const ushort4*)(feat + (size_t)s1*256 + l*4);
    ushort4 f2 = *(const ushort4*)(feat + (size_t)s2*256 + l*4);
    ushort4 f3 = *(const ushort4*)(feat + (size_t)s3*256 + l*4);
    ax += e0*b2f(f0.x) + e1*b2f(f1.x) + e2*b2f(f2.x) + e3*b2f(f3.x);
    ay += e0*b2f(f0.y) + e1*b2f(f1.y) + e2*b2f(f2.y) + e3*b2f(f3.y);
    az += e0*b2f(f0.z) + e1*b2f(f1.z) + e2*b2f(f2.z) + e3*b2f(f3.z);
    aw += e0*b2f(f0.w) + e1*b2f(f1.w) + e2*b2f(f2.w) + e3*b2f(f3.w);
  }
  for (; i < o1; ++i){
    int s0 = srcs[i];
    float e0 = es[(size_t)i*4 + h];
    ushort4 f0 = *(const ushort4*)(feat + (size_t)s0*256 + l*4);
    ax += e0*b2f(f0.x); ay += e0*b2f(f0.y); az += e0*b2f(f0.z); aw += e0*b2f(f0.w);
  }
  float rc = recs[n*4+h];
  float vx = ax*rc, vy = ay*rc, vz = az*rc, vw = aw*rc;
  if (RES){
    ushort4 r4 = *(const ushort4*)(resid + (size_t)n*256 + l*4);
    vx += b2f(r4.x); vy += b2f(r4.y); vz += b2f(r4.z); vw += b2f(r4.w);
  }
  vx = vx > 0.f ? vx : expm1f(vx);
  vy = vy > 0.f ? vy : expm1f(vy);
  vz = vz > 0.f ? vz : expm1f(vz);
  vw = vw > 0.f ? vw : expm1f(vw);
  if (outf){ float4 v; v.x=vx; v.y=vy; v.z=vz; v.w=vw; *(float4*)(outf + (size_t)n*256 + l*4) = v; }
  ushort4 ob; ob.x=f2b(vx); ob.y=f2b(vy); ob.z=f2b(vz); ob.w=f2b(vw);
  *(ushort4*)(outb + (size_t)n*256 + l*4) = ob;
}

// ---------- output-layer aggregation: OUT=40, batched 4-edge flattened gather ----------
// Per wave (node): 4 edges/group, feat row = 80 dwords; 4*80=320 dwords = 5 regs x 64 lanes.
__global__ __launch_bounds__(256) void k_agg_out(const u16* __restrict__ feat, const float* __restrict__ es,
    const float* __restrict__ recs, const int* __restrict__ off, const int* __restrict__ srcs,
    const u16* __restrict__ reso, float* __restrict__ logits){
  __shared__ float2 red[4][4][80];   // [wave][slot][dword]  = 10240 B
  __shared__ float fin[4][160];      // 2560 B
  const int l = threadIdx.x & 63, w = threadIdx.x >> 6;
  const int n = blockIdx.x*4 + w;
  const int o0 = off[n], o1 = off[n+1];
  int sArr[5], dpArr[5], hArr[5];
  #pragma unroll
  for (int r=0;r<5;++r){
    int p = r*64 + l;
    sArr[r] = p/80; dpArr[r] = p%80; hArr[r] = dpArr[r]/20;
  }
  float2 acc[5];
  #pragma unroll
  for (int r=0;r<5;++r){ acc[r].x=0.f; acc[r].y=0.f; }
  for (int i0 = o0; i0 < o1; i0 += 4){
    int cnt = o1 - i0;
    #pragma unroll
    for (int r=0;r<5;++r){
      int s = sArr[r];
      bool valid = s < cnt;
      int e = valid ? (i0 + s) : i0;
      int sv = srcs[e];
      float al = es[(size_t)e*4 + hArr[r]];
      ushort2 f = *(const ushort2*)(feat + (size_t)sv*160 + dpArr[r]*2);
      if (!valid) al = 0.f;
      acc[r].x += al * b2f(f.x);
      acc[r].y += al * b2f(f.y);
    }
  }
  #pragma unroll
  for (int r=0;r<5;++r) red[w][sArr[r]][dpArr[r]] = acc[r];
  __syncthreads();
  float4 rc = ((const float4*)recs)[n];
  const float* rcp = (const float*)&rc;
  // 80 dwords over 64 lanes: dp = l, and dp = 64+l for l<16
  {
    int dp = l;
    float vx = red[w][0][dp].x + red[w][1][dp].x + red[w][2][dp].x + red[w][3][dp].x;
    float vy = red[w][0][dp].y + red[w][1][dp].y + red[w][2][dp].y + red[w][3][dp].y;
    float r0 = rcp[dp/20];
    ushort2 rr = *(const ushort2*)(reso + (size_t)n*160 + dp*2);
    fin[w][dp*2]   = vx*r0 + b2f(rr.x);
    fin[w][dp*2+1] = vy*r0 + b2f(rr.y);
  }
  if (l < 16){
    int dp = 64 + l;
    float vx = red[w][0][dp].x + red[w][1][dp].x + red[w][2][dp].x + red[w][3][dp].x;
    float vy = red[w][0][dp].y + red[w][1][dp].y + red[w][2][dp].y + red[w][3][dp].y;
    float r0 = rcp[3];
    ushort2 rr = *(const ushort2*)(reso + (size_t)n*160 + dp*2);
    fin[w][dp*2]   = vx*r0 + b2f(rr.x);
    fin[w][dp*2+1] = vy*r0 + b2f(rr.y);
  }
  __syncthreads();
  if (l < 40) logits[(size_t)n*40 + l] = 0.25f*(fin[w][l]+fin[w][l+40]+fin[w][l+80]+fin[w][l+120]);
}

extern "C" void kernel_launch(void* const* d_in, const int* in_sizes, int n_in,
                              void* d_out, int out_size, void* d_ws, size_t ws_size,
                              hipStream_t stream){
  const float* inputs = (const float*)d_in[0];
  const int*   src    = (const int*)d_in[1];
  const int*   dst    = (const int*)d_in[2];
  const float* W0  = (const float*)d_in[3];
  const float* al0 = (const float*)d_in[4];
  const float* ar0 = (const float*)d_in[5];
  const float* W1  = (const float*)d_in[6];
  const float* al1 = (const float*)d_in[7];
  const float* ar1 = (const float*)d_in[8];
  const float* Wo  = (const float*)d_in[9];
  const float* alo = (const float*)d_in[10];
  const float* aro = (const float*)d_in[11];
  const float* rWo = (const float*)d_in[12];
  const float* fcW = (const float*)d_in[13];

  float* out = (float*)d_out;
  float* out_logits = out;                 // [50000,40]
  float* out_h      = out + 2000000;       // [50000,256]
  float* out_seq    = out + 14800000;      // [50000,64]

  char* ws = (char*)d_ws;
  size_t o = 0;
  auto alc = [&](size_t bytes){ size_t r = o; o += (bytes + 255) & ~(size_t)255; return r; };
  size_t oXb   = alc((size_t)NN*256*2);
  size_t oFA   = alc((size_t)NN*256*2);
  size_t oFB   = alc((size_t)NN*256*2);
  size_t oEs   = alc((size_t)EE*4*4);
  size_t oSrcs = alc((size_t)EE*4);
  size_t oOff  = alc((size_t)(NN+1)*4);
  size_t oCnt  = alc((size_t)(NN+1)*4);
  size_t oCur  = alc((size_t)NN*4);
  size_t oPart = alc(64*4);
  size_t oEl   = alc((size_t)NN*4*4);
  size_t oEr   = alc((size_t)NN*4*4);
  size_t oRecs = alc((size_t)NN*4*4);
  size_t oReso = alc((size_t)NN*160*2);
  size_t oW0b  = alc(256*256*2);
  size_t oW1b  = alc(256*256*2);
  size_t oWcat = alc(256*320*2);
  size_t oFcb  = alc(256*64*2);
  if (ws_size < o) return;

  u16* Xb   = (u16*)(ws + oXb);
  u16* fA   = (u16*)(ws + oFA);
  u16* fB   = (u16*)(ws + oFB);
  float* es = (float*)(ws + oEs);
  int* srcs = (int*)(ws + oSrcs);
  int* off  = (int*)(ws + oOff);
  int* cnt  = (int*)(ws + oCnt);
  int* cur  = (int*)(ws + oCur);
  int* part = (int*)(ws + oPart);
  float* el = (float*)(ws + oEl);
  float* er = (float*)(ws + oEr);
  float* recs = (float*)(ws + oRecs);
  u16* reso = (u16*)(ws + oReso);
  u16* W0b  = (u16*)(ws + oW0b);
  u16* W1b  = (u16*)(ws + oW1b);
  u16* Wcat = (u16*)(ws + oWcat);
  u16* fcb  = (u16*)(ws + oFcb);

  // ---- converts ----
  k_f2b4<<<(NN*256/4 + 255)/256, 256, 0, stream>>>(inputs, Xb, NN*256/4);
  k_f2b4<<<(65536/4 + 255)/256, 256, 0, stream>>>(W0, W0b, 65536/4);
  k_f2b4<<<(65536/4 + 255)/256, 256, 0, stream>>>(W1, W1b, 65536/4);
  k_catWo<<<(256*320 + 255)/256, 256, 0, stream>>>(rWo, Wo, Wcat);
  k_f2b4<<<(16384/4 + 255)/256, 256, 0, stream>>>(fcW, fcb, 16384/4);

  // ---- CSR ----
  hipMemsetAsync(cnt, 0, (size_t)(NN+1)*4, stream);
  k_count<<<(EE+255)/256, 256, 0, stream>>>(dst, cnt);
  const int NP1 = NN+1, NB = (NP1 + 1023)/1024;
  k_scan_blocks<<<NB, 256, 0, stream>>>(cnt, off, part, NP1);
  k_scan_part<<<1, 64, 0, stream>>>(part, NB);
  k_addback<<<NB, 256, 0, stream>>>(off, part, NP1);
  k_copy<<<(NN+255)/256, 256, 0, stream>>>(off, cur, NN);
  k_scatter<<<(EE+255)/256, 256, 0, stream>>>(src, dst, cur, srcs);

  dim3 gN256((NN+255)/256, 4), gN320((NN+255)/256, 5), gN64((NN+255)/256, 1);

  // ---- seq_fts = X @ fc_W (f32 out) ----
  k_gemm<0><<<gN64, 256, 0, stream>>>(Xb, fcb, out_seq, nullptr, NN, 64);

  // ---- layer 0 ----
  k_gemm<1><<<gN256, 256, 0, stream>>>(Xb, W0b, fA, nullptr, NN, 256);
  k_eler<<<(NN*64 + 255)/256, 256, 0, stream>>>(fA, al0, ar0, el, er, 64, 256);
  k_soft<<<(NN+255)/256, 256, 0, stream>>>(el, er, srcs, off, es, recs);
  k_agg64<false><<<NN/4, 256, 0, stream>>>(fA, es, recs, off, srcs, nullptr, nullptr, fB);

  // ---- layer 1 ----
  k_gemm<1><<<gN256, 256, 0, stream>>>(fB, W1b, fA, nullptr, NN, 256);
  k_eler<<<(NN*64 + 255)/256, 256, 0, stream>>>(fA, al1, ar1, el, er, 64, 256);
  k_soft<<<(NN+255)/256, 256, 0, stream>>>(el, er, srcs, off, es, recs);
  k_agg64<true><<<NN/4, 256, 0, stream>>>(fA, es, recs, off, srcs, fB, out_h, fB);

  // ---- output layer: fused [reso | feat] GEMM ----
  k_gemm<2><<<gN320, 256, 0, stream>>>(fB, Wcat, reso, fA, NN, 320);
  k_eler<<<(NN*64 + 255)/256, 256, 0, stream>>>(fA, alo, aro, el, er, 40, 160);
  k_soft<<<(NN+255)/256, 256, 0, stream>>>(el, er, srcs, off, es, recs);
  k_agg_out<<<NN/4, 256, 0, stream>>>(fA, es, recs, off, srcs, reso, out_logits);
}